// Round 15
// baseline (2213.079 us; speedup 1.0000x reference)
//
#include <hip/hip_runtime.h>
#include <hip/hip_bf16.h>

// UltimateExcellencePiMoE on MI355X.
// B=4, S=256, D=1024, E=2048, H=16, HD=128, NE=4, K(topk)=2.
// R15: R11-verified GEMM (single-buffer BK=64) + R8-verified LSTM tail
// (s_sleep poll). Weight conversion: 11 verified convf2b launches, all
// up-front, into a fixed-offset bf16 arena (R14's convall used __constant__
// + struct args and produced zero output -> reverted to proven primitives).

typedef unsigned short u16;
typedef unsigned int u32;
typedef unsigned long long u64;
typedef __attribute__((ext_vector_type(8))) short short8;
typedef __attribute__((ext_vector_type(4))) float f32x4;

#define DEV static __device__ __forceinline__

DEV u16 f2bf(float f){ u32 u = __float_as_uint(f); u += 0x7fffu + ((u >> 16) & 1u); return (u16)(u >> 16); }
DEV float bf2f(u16 s){ return __uint_as_float(((u32)s) << 16); }
DEV u32 pk2(float a, float b){ return (u32)f2bf(a) | ((u32)f2bf(b) << 16); }
DEV float sigf(float x){ return 1.f / (1.f + __expf(-x)); }
DEV float sig_fast(float x){ return __builtin_amdgcn_rcpf(1.f + __expf(-x)); }
DEV float tanh_fast(float x){
  float ax = fabsf(x);
  float t = __expf(-2.f * ax);
  float r = (1.f - t) * __builtin_amdgcn_rcpf(1.f + t);
  return copysignf(r, x);
}

// async global->LDS, 16B per lane; LDS dest = wave-uniform base + lane*16.
DEV void gld16(u16* lds, const u16* g){
  __builtin_amdgcn_global_load_lds((const __attribute__((address_space(1))) u32*)g,
                                   (__attribute__((address_space(3))) u32*)lds, 16, 0, 0);
}

// 2-stat block reduction, assumes 256 threads (4 waves). red: float[16] LDS.
DEV void bred2(float& s, float& ss, float* red){
  #pragma unroll
  for (int o = 32; o; o >>= 1){ s += __shfl_xor(s, o); ss += __shfl_xor(ss, o); }
  int wv = threadIdx.x >> 6, ln = threadIdx.x & 63;
  if (ln == 0){ red[wv] = s; red[8 + wv] = ss; }
  __syncthreads();
  s = red[0] + red[1] + red[2] + red[3];
  ss = red[8] + red[9] + red[10] + red[11];
}

// ---------------- generic batched GEMM: C = act(scale * (A @ B^T) + bias) ----
// Tile 128x128, BK=64 stored as two stacked 32-col halves (4096 elems each).
// BMODE 1: A,B bf16 via global_load_lds. BMODE 0: B fp32 in-kernel (fallback).
template<int BMODE, int SC, bool BIAS, bool RELU, bool SCALE>
__global__ void __launch_bounds__(256, 2) gemm_bt(
    const u16* __restrict__ A, const void* __restrict__ Bv,
    u16* __restrict__ C0, u16* __restrict__ C1, u16* __restrict__ C2,
    const float* __restrict__ bias,
    int N, int K, int lda, int ldb,
    long long sA, long long sB, long long sC, int sBias,
    int nbm, int nbn, float scale)
{
  __shared__ u16 As[8192];   // 16 KB: [half2][128][32]
  __shared__ u16 Bs[8192];   // 16 KB
  int bid = blockIdx.x;
  int per = nbm * nbn;
  int batch = bid / per;
  int rem = bid - batch * per;
  int bm = rem % nbm, bn = rem / nbm;
  int t = threadIdx.x;
  int wave = t >> 6, lane = t & 63, fm = lane & 15, kg = lane >> 4;
  int wm = (wave >> 1) * 64, wn = (wave & 1) * 64;
  const u16* Ab = A + (size_t)batch * sA + (size_t)(bm * 128) * lda;
  const u16* Bb16 = nullptr;
  if constexpr (BMODE == 1)
    Bb16 = (const u16*)Bv + (size_t)batch * sB + (size_t)(bn * 128) * ldb;
  int aoff[4], boff[4];
  #pragma unroll
  for (int mi = 0; mi < 4; ++mi) aoff[mi] = (wm + mi * 16 + fm) * 32 + kg * 8;
  #pragma unroll
  for (int ni = 0; ni < 4; ++ni) boff[ni] = (wn + ni * 16 + fm) * 32 + kg * 8;
  int rr_[4], gc_[4];
  #pragma unroll
  for (int q = 0; q < 4; ++q){
    int c = q * 256 + t;
    rr_[q] = (c >> 2) & 127;
    gc_[q] = (c >> 9) * 32 + (c & 3) * 8;
  }
  f32x4 zero = {0.f, 0.f, 0.f, 0.f};
  f32x4 acc[4][4];
  #pragma unroll
  for (int i = 0; i < 4; ++i)
    #pragma unroll
    for (int j = 0; j < 4; ++j) acc[i][j] = zero;
  int nk = K >> 6;
  for (int ks = 0; ks < nk; ++ks){
    int k0 = ks << 6;
    if constexpr (BMODE == 1){
      #pragma unroll
      for (int q = 0; q < 4; ++q){
        int c = q * 256 + t;
        gld16(&As[c * 8], Ab + (size_t)rr_[q] * lda + k0 + gc_[q]);
        gld16(&Bs[c * 8], Bb16 + (size_t)rr_[q] * ldb + k0 + gc_[q]);
      }
    } else {
      #pragma unroll
      for (int q = 0; q < 4; ++q){
        int c = q * 256 + t;
        gld16(&As[c * 8], Ab + (size_t)rr_[q] * lda + k0 + gc_[q]);
      }
      int n = t >> 1, half = t & 1;
      const float* Bb = (const float*)Bv + (size_t)batch * sB + (size_t)(bn * 128 + n) * ldb + k0 + half * 32;
      u16* bd = &Bs[half * 4096 + n * 32];
      #pragma unroll
      for (int j = 0; j < 4; ++j){
        float4 fa = *(const float4*)(Bb + j * 8);
        float4 fb = *(const float4*)(Bb + j * 8 + 4);
        uint4 o;
        o.x = pk2(fa.x, fa.y); o.y = pk2(fa.z, fa.w);
        o.z = pk2(fb.x, fb.y); o.w = pk2(fb.z, fb.w);
        *(uint4*)(bd + j * 8) = o;
      }
    }
    __syncthreads();
    #pragma unroll
    for (int ki = 0; ki < 2; ++ki){
      short8 afr[4], bfr[4];
      #pragma unroll
      for (int mi = 0; mi < 4; ++mi) afr[mi] = *(const short8*)&As[ki * 4096 + aoff[mi]];
      #pragma unroll
      for (int ni = 0; ni < 4; ++ni) bfr[ni] = *(const short8*)&Bs[ki * 4096 + boff[ni]];
      #pragma unroll
      for (int mi = 0; mi < 4; ++mi)
        #pragma unroll
        for (int ni = 0; ni < 4; ++ni)
          acc[mi][ni] = __builtin_amdgcn_mfma_f32_16x16x32_bf16(afr[mi], bfr[ni], acc[mi][ni], 0, 0, 0);
    }
    __syncthreads();
  }
  #pragma unroll
  for (int mi = 0; mi < 4; ++mi){
    #pragma unroll
    for (int ni = 0; ni < 4; ++ni){
      f32x4 v = acc[mi][ni];
      int gm0 = bm * 128 + wm + mi * 16 + kg * 4;
      int gn = bn * 128 + wn + ni * 16 + fm;
      float bv = 0.f;
      if constexpr (BIAS) bv = bias[(size_t)batch * sBias + gn];
      #pragma unroll
      for (int jj = 0; jj < 4; ++jj){
        float xv = v[jj];
        if constexpr (SCALE) xv *= scale;
        if constexpr (BIAS) xv += bv;
        if constexpr (RELU) xv = fmaxf(xv, 0.f);
        int gm = gm0 + jj;
        u16 ov = f2bf(xv);
        if constexpr (SC == 0){
          C0[(size_t)batch * sC + (size_t)gm * N + gn] = ov;
        } else if constexpr (SC == 1){
          int which = gn >> 11, hh = (gn >> 7) & 15, d = gn & 127;
          int b_ = gm >> 8, s_ = gm & 255;
          size_t hb = ((size_t)batch * 4 + b_) * 16 + hh;
          if (which == 0)      C0[(hb * 256 + s_) * 128 + d] = ov;       // Q[e,b,h,s,d]
          else if (which == 1) C1[(hb * 256 + s_) * 128 + d] = ov;       // K[e,b,h,s,d]
          else                 C2[(hb * 128 + d) * 256 + s_] = ov;       // V^T[e,b,h,d,s]
        } else {
          int e_ = batch >> 6, b_ = (batch >> 4) & 3, hh = batch & 15;
          C0[(((size_t)e_ * 4 + b_) * 256 + gm) * 2048 + hh * 128 + gn] = ov;
        }
      }
    }
  }
}

// ---------------- small kernels -------------------------------------------
__global__ void __launch_bounds__(256, 4) convf2b(const float* __restrict__ src, u16* __restrict__ dst, int n8){
  int stride = gridDim.x * 256;
  for (int i = blockIdx.x * 256 + threadIdx.x; i < n8; i += stride){
    float4 a = *(const float4*)(src + (size_t)i * 8);
    float4 b = *(const float4*)(src + (size_t)i * 8 + 4);
    uint4 o;
    o.x = pk2(a.x, a.y); o.y = pk2(a.z, a.w); o.z = pk2(b.x, b.y); o.w = pk2(b.z, b.w);
    *(uint4*)(dst + (size_t)i * 8) = o;
  }
}

__global__ void __launch_bounds__(256, 4) convert_x(const float* __restrict__ x, u16* __restrict__ xb){
  int idx = blockIdx.x * 256 + threadIdx.x;
  float4 a = *(const float4*)(x + (size_t)idx * 8);
  float4 b = *(const float4*)(x + (size_t)idx * 8 + 4);
  uint4 o;
  o.x = pk2(a.x, a.y); o.y = pk2(a.z, a.w); o.z = pk2(b.x, b.y); o.w = pk2(b.z, b.w);
  *(uint4*)(xb + (size_t)idx * 8) = o;
}

__global__ void __launch_bounds__(256, 4) comb_bias(const float* __restrict__ a, const float* __restrict__ b, float* __restrict__ o){
  int idx = blockIdx.x * 256 + threadIdx.x;
  float4 va = *(const float4*)(a + (size_t)idx * 4);
  float4 vb = *(const float4*)(b + (size_t)idx * 4);
  float4 r; r.x = va.x + vb.x; r.y = va.y + vb.y; r.z = va.z + vb.z; r.w = va.w + vb.w;
  *(float4*)(o + (size_t)idx * 4) = r;
}

__global__ void __launch_bounds__(256, 4) gate_pool(const float* __restrict__ x, float* __restrict__ pooled){
  int id = blockIdx.x * 256 + threadIdx.x;
  int b = id >> 10, d = id & 1023;
  const float* p = x + (size_t)b * 262144 + d;
  float s = 0.f;
  for (int si = 0; si < 256; ++si) s += p[si * 1024];
  pooled[id] = s * (1.f / 256.f);
}

__global__ void __launch_bounds__(256, 2) gate_top2(const float* __restrict__ pooled,
    const float* __restrict__ gw, const float* __restrict__ gb, float* __restrict__ wout)
{
  __shared__ float part[16][16];
  __shared__ float lg[4][4];
  int t = threadIdx.x;
  int pair = t >> 4, l = t & 15;
  int b = pair >> 2, e = pair & 3;
  float s = 0.f;
  for (int d = l; d < 1024; d += 16) s += pooled[b * 1024 + d] * gw[d * 4 + e];
  part[pair][l] = s;
  __syncthreads();
  if (t < 16){
    float v = 0.f;
    #pragma unroll
    for (int i = 0; i < 16; ++i) v += part[t][i];
    lg[t >> 2][t & 3] = v + gb[t & 3];
  }
  __syncthreads();
  if (t < 4){
    float p[4];
    float mx = -1e30f;
    for (int i = 0; i < 4; ++i) mx = fmaxf(mx, lg[t][i]);
    float sum = 0.f;
    for (int i = 0; i < 4; ++i){ p[i] = expf(lg[t][i] - mx); sum += p[i]; }
    for (int i = 0; i < 4; ++i) p[i] /= sum;
    int i1 = 0;
    for (int i = 1; i < 4; ++i) if (p[i] > p[i1]) i1 = i;
    int i2 = (i1 == 0) ? 1 : 0;
    for (int i = 0; i < 4; ++i) if (i != i1 && p[i] > p[i2]) i2 = i;
    float den = p[i1] + p[i2];
    float w4[4] = {0.f, 0.f, 0.f, 0.f};
    w4[i1] = p[i1] / den; w4[i2] = p[i2] / den;
    for (int i = 0; i < 4; ++i) wout[t * 4 + i] = w4[i];
  }
}

__global__ void __launch_bounds__(256, 4) ln2048(const u16* __restrict__ in, u16* __restrict__ out,
                                                 const float* __restrict__ gg, const float* __restrict__ bb)
{
  __shared__ float red[16];
  int row = blockIdx.x, e = row >> 10, t = threadIdx.x;
  uint4 v = *(const uint4*)(in + (size_t)row * 2048 + t * 8);
  float f[8] = { bf2f(v.x & 0xffff), bf2f(v.x >> 16), bf2f(v.y & 0xffff), bf2f(v.y >> 16),
                 bf2f(v.z & 0xffff), bf2f(v.z >> 16), bf2f(v.w & 0xffff), bf2f(v.w >> 16) };
  float s = 0.f, ss = 0.f;
  #pragma unroll
  for (int i = 0; i < 8; ++i){ s += f[i]; ss += f[i] * f[i]; }
  bred2(s, ss, red);
  float mean = s * (1.f / 2048.f);
  float var = ss * (1.f / 2048.f) - mean * mean;
  float rstd = rsqrtf(var + 1e-5f);
  const float* g4 = gg + (size_t)e * 2048 + t * 8;
  const float* b4 = bb + (size_t)e * 2048 + t * 8;
  float4 ga = *(const float4*)g4, gb2 = *(const float4*)(g4 + 4);
  float4 ba = *(const float4*)b4, bb2 = *(const float4*)(b4 + 4);
  float r[8];
  r[0] = (f[0] - mean) * rstd * ga.x + ba.x; r[1] = (f[1] - mean) * rstd * ga.y + ba.y;
  r[2] = (f[2] - mean) * rstd * ga.z + ba.z; r[3] = (f[3] - mean) * rstd * ga.w + ba.w;
  r[4] = (f[4] - mean) * rstd * gb2.x + bb2.x; r[5] = (f[5] - mean) * rstd * gb2.y + bb2.y;
  r[6] = (f[6] - mean) * rstd * gb2.z + bb2.z; r[7] = (f[7] - mean) * rstd * gb2.w + bb2.w;
  uint4 o; o.x = pk2(r[0], r[1]); o.y = pk2(r[2], r[3]); o.z = pk2(r[4], r[5]); o.w = pk2(r[6], r[7]);
  *(uint4*)(out + (size_t)row * 2048 + t * 8) = o;
}

__global__ void __launch_bounds__(256, 4) softmax256(u16* __restrict__ sp){
  int row = blockIdx.x * 4 + (threadIdx.x >> 6);
  int ln = threadIdx.x & 63;
  u16* p = sp + (size_t)row * 256 + ln * 4;
  uint2 v = *(const uint2*)p;
  float f0 = bf2f(v.x & 0xffff), f1 = bf2f(v.x >> 16), f2 = bf2f(v.y & 0xffff), f3 = bf2f(v.y >> 16);
  float mx = fmaxf(fmaxf(f0, f1), fmaxf(f2, f3));
  #pragma unroll
  for (int o = 32; o; o >>= 1) mx = fmaxf(mx, __shfl_xor(mx, o));
  float e0 = __expf(f0 - mx), e1 = __expf(f1 - mx), e2 = __expf(f2 - mx), e3 = __expf(f3 - mx);
  float s = e0 + e1 + e2 + e3;
  #pragma unroll
  for (int o = 32; o; o >>= 1) s += __shfl_xor(s, o);
  float inv = 1.f / s;
  uint2 ov; ov.x = pk2(e0 * inv, e1 * inv); ov.y = pk2(e2 * inv, e3 * inv);
  *(uint2*)p = ov;
}

// W_hh (e,4E,E) fp32 -> per-wave MFMA B-fragment layout Wf[e][nt][kt][lane][8] bf16.
__global__ void __launch_bounds__(256, 2) wf_convert(const float* __restrict__ whh, u16* __restrict__ Wf){
  __shared__ float ls[16 * 260];
  int bid = blockIdx.x;
  int e = bid >> 12, nt = (bid >> 3) & 511, ktg = bid & 7;
  int t = threadIdx.x;
  const float* src = whh + ((size_t)e * 8192 + nt * 16) * 2048 + ktg * 256;
  #pragma unroll
  for (int it = 0; it < 4; ++it){
    int idx = it * 256 + t;
    int r = idx >> 6, f4 = (idx & 63) * 4;
    *(float4*)&ls[r * 260 + f4] = *(const float4*)(src + (size_t)r * 2048 + f4);
  }
  __syncthreads();
  #pragma unroll
  for (int it = 0; it < 2; ++it){
    int idx = it * 256 + t;
    int ktl = idx >> 6, lane = idx & 63;
    int r = lane & 15, kloc = ktl * 32 + (lane >> 4) * 8;
    float4 va = *(const float4*)&ls[r * 260 + kloc];
    float4 vb = *(const float4*)&ls[r * 260 + kloc + 4];
    uint4 o; o.x = pk2(va.x, va.y); o.y = pk2(va.z, va.w); o.z = pk2(vb.x, vb.y); o.w = pk2(vb.z, vb.w);
    size_t chunk = ((size_t)(e * 512 + nt) * 64 + (ktg * 8 + ktl)) * 64 + lane;
    *(uint4*)(Wf + chunk * 8) = o;
  }
}

// ---------------- persistent LSTM recurrence --------------------------------
// grid = 256 blocks (1/CU via ~147KB LDS) x 512 threads (8 waves).
// R8-verified tail (976us) with s_sleep poll.
__global__ void __launch_bounds__(512, 2) lstm_persist(
    const u16* __restrict__ Wf, const u16* __restrict__ pre,
    u16* hbuf,                 // [2][e(4)][b(4)][2048] bf16
    u16* __restrict__ mout,    // [(e*4+b)*256+step][2048] bf16
    u32* flags)                // [4][64][16] u32 (64B stride per block)
{
  __shared__ u16 pinW[8 * 16 * 512];      // 128 KB
  __shared__ u16 hA[64 * 136];            // 17 KB: [kt64][kg4][r4][8] +pad
  __shared__ float g_s[8][16][4];         // 2 KB
  int blk = blockIdx.x;
  int e = blk & 3, be = blk >> 2;         // XCD-local expert mapping
  int jb = be * 32;
  int t = threadIdx.x;
  int wave = t >> 6, lane = t & 63;
  int fm = lane & 15, kg = lane >> 4;
  int gate = wave >> 1, half = wave & 1;
  int nt = gate * 128 + (jb >> 4) + half;
  const u16* wp = Wf + (((size_t)(e * 512 + nt) * 64) * 64 + lane) * 8;
  #pragma unroll
  for (int kt = 0; kt < 16; ++kt)
    *(uint4*)&pinW[(wave * 16 + kt) * 512 + lane * 8] = *(const uint4*)(wp + (size_t)kt * 512);
  short8 wreg[40];
  #pragma unroll
  for (int i = 0; i < 40; ++i)
    wreg[i] = *(const short8*)(wp + (size_t)(16 + i) * 512);
  const u16* wps = wp + (size_t)56 * 512;
  const u16* arow = &hA[kg * 32 + (fm & 3) * 8];   // duplicate-row A address
  int b_ = t >> 4, jp = t & 15;                    // epilogue mapping (t<64)
  int w0 = jp >> 3, j0 = jp * 2, c0 = j0 & 15, c1 = c0 + 1;
  float creg0 = 0.f, creg1 = 0.f;
  u32* myflags = flags + e * 1024;                 // 64 blocks * 16 u32
  size_t moutbase = ((size_t)(e * 4 + b_) * 256) * 2048 + jb + j0;
  for (int step = 0; step < 256; ++step){
    int par = step & 1;
    u32 pi = 0, pf = 0, pg = 0, po = 0;
    if (t < 64){
      size_t prebase = ((size_t)(e * 4 + b_) * 256 + step) * 8192 + jb + j0;
      pi = *(const u32*)(pre + prebase);
      pf = *(const u32*)(pre + prebase + 2048);
      pg = *(const u32*)(pre + prebase + 4096);
      po = *(const u32*)(pre + prebase + 6144);
    }
    const u16* hsrc = hbuf + par * 32768 + e * 8192;
    #pragma unroll
    for (int it = 0; it < 4; ++it){
      int c8 = it * 512 + t;
      int r = c8 >> 9, w4 = c8 & 511;
      u64 v = __hip_atomic_load((const u64*)(hsrc + r * 2048 + w4 * 4),
                                __ATOMIC_RELAXED, __HIP_MEMORY_SCOPE_AGENT);
      int di = (w4 >> 3) * 136 + ((w4 >> 1) & 3) * 32 + r * 8 + (w4 & 1) * 4;
      *(u64*)&hA[di] = v;
    }
    __syncthreads();                      // sync1: hA ready
    short8 wtmp[8];
    #pragma unroll
    for (int i = 0; i < 8; ++i)
      wtmp[i] = *(const short8*)(wps + (size_t)i * 512);
    f32x4 acc[4];
    #pragma unroll
    for (int i = 0; i < 4; ++i) acc[i] = (f32x4){0.f, 0.f, 0.f, 0.f};
    #pragma unroll
    for (int kt = 0; kt < 16; ++kt){
      short8 a = *(const short8*)(arow + kt * 136);
      short8 b = *(const short8*)&pinW[(wave * 16 + kt) * 512 + lane * 8];
      acc[kt & 3] = __builtin_amdgcn_mfma_f32_16x16x32_bf16(a, b, acc[kt & 3], 0, 0, 0);
    }
    #pragma unroll
    for (int i = 0; i < 40; ++i){
      short8 a = *(const short8*)(arow + (16 + i) * 136);
      acc[i & 3] = __builtin_amdgcn_mfma_f32_16x16x32_bf16(a, wreg[i], acc[i & 3], 0, 0, 0);
    }
    #pragma unroll
    for (int i = 0; i < 8; ++i){
      short8 a = *(const short8*)(arow + (56 + i) * 136);
      acc[i & 3] = __builtin_amdgcn_mfma_f32_16x16x32_bf16(a, wtmp[i], acc[i & 3], 0, 0, 0);
    }
    f32x4 accs = (acc[0] + acc[1]) + (acc[2] + acc[3]);
    if (lane < 16){
      #pragma unroll
      for (int jj = 0; jj < 4; ++jj) g_s[wave][lane][jj] = accs[jj];
    }
    __syncthreads();                      // sync2: g_s ready
    if (t < 64){
      float gi0 = g_s[0 + w0][c0][b_] + bf2f(pi & 0xffff), gi1 = g_s[0 + w0][c1][b_] + bf2f(pi >> 16);
      float gf0 = g_s[2 + w0][c0][b_] + bf2f(pf & 0xffff), gf1 = g_s[2 + w0][c1][b_] + bf2f(pf >> 16);
      float gg0 = g_s[4 + w0][c0][b_] + bf2f(pg & 0xffff), gg1 = g_s[4 + w0][c1][b_] + bf2f(pg >> 16);
      float go0 = g_s[6 + w0][c0][b_] + bf2f(po & 0xffff), go1 = g_s[6 + w0][c1][b_] + bf2f(po >> 16);
      float c0v = sig_fast(gf0) * creg0 + sig_fast(gi0) * tanh_fast(gg0);
      float c1v = sig_fast(gf1) * creg1 + sig_fast(gi1) * tanh_fast(gg1);
      float h0 = sig_fast(go0) * tanh_fast(c0v);
      float h1 = sig_fast(go1) * tanh_fast(c1v);
      creg0 = c0v; creg1 = c1v;
      u32 hv = pk2(h0, h1);
      __hip_atomic_store((u32*)(hbuf + (par ^ 1) * 32768 + e * 8192 + b_ * 2048 + jb + j0), hv,
                         __ATOMIC_RELAXED, __HIP_MEMORY_SCOPE_AGENT);
      *(u32*)(mout + moutbase + (size_t)step * 2048) = hv;   // ack overlaps h ack
    }
    __syncthreads();  // sync3: drains h (coherence) + mout (HBM) concurrently
    if (step < 255 && t < 64){
      if (t == 0)
        __hip_atomic_store(&myflags[be * 16], (u32)(step + 1), __ATOMIC_RELAXED, __HIP_MEMORY_SCOPE_AGENT);
      u32 fuel = 0;
      do {
        u32 f = __hip_atomic_load(&myflags[t * 16], __ATOMIC_RELAXED, __HIP_MEMORY_SCOPE_AGENT);
        if (!__any(f < (u32)(step + 1))) break;
        __builtin_amdgcn_s_sleep(1);
      } while (++fuel < (1u << 22));   // bounded: degrades instead of hanging
    }
    __syncthreads();  // loop-end: nothing outstanding -> cheap
  }
}

__global__ void __launch_bounds__(256, 4) eo_kernel(const u16* __restrict__ ep, const u16* __restrict__ op, u16* __restrict__ eo){
  int idx = blockIdx.x * 256 + threadIdx.x;
  uint4 ev = *(const uint4*)(ep + (size_t)idx * 8);
  uint4 ov = *(const uint4*)(op + (size_t)idx * 8);
  u32 e4[4] = {ev.x, ev.y, ev.z, ev.w};
  u32 o4[4] = {ov.x, ov.y, ov.z, ov.w};
  uint4 r;
  u32* rp = (u32*)&r;
  #pragma unroll
  for (int q = 0; q < 4; ++q){
    float a0 = sigf(bf2f(e4[q] & 0xffff)) * tanhf(bf2f(o4[q] & 0xffff));
    float a1 = sigf(bf2f(e4[q] >> 16)) * tanhf(bf2f(o4[q] >> 16));
    rp[q] = pk2(a0, a1);
  }
  *(uint4*)(eo + (size_t)idx * 8) = r;
}

__global__ void __launch_bounds__(256, 2) final_combine(const u16* __restrict__ decp, const float* __restrict__ wg,
    const float* __restrict__ gg, const float* __restrict__ bb, float* __restrict__ out)
{
  __shared__ float red[16];
  int tok = blockIdx.x;
  int b = tok >> 8;
  int t = threadIdx.x;
  float a0 = 0.f, a1 = 0.f, a2 = 0.f, a3 = 0.f;
  for (int e = 0; e < 4; ++e){
    const u16* p = decp + ((size_t)e * 1024 + tok) * 1024 + t * 4;
    uint2 v = *(const uint2*)p;
    float f0 = bf2f(v.x & 0xffff), f1 = bf2f(v.x >> 16), f2 = bf2f(v.y & 0xffff), f3 = bf2f(v.y >> 16);
    float s = f0 + f1 + f2 + f3;
    float ss = f0 * f0 + f1 * f1 + f2 * f2 + f3 * f3;
    bred2(s, ss, red);
    float mean = s * (1.f / 1024.f);
    float var = ss * (1.f / 1024.f) - mean * mean;
    float rstd = rsqrtf(var + 1e-5f);
    float we = wg[b * 4 + e];
    float4 gv = *(const float4*)(gg + (size_t)e * 1024 + t * 4);
    float4 bv = *(const float4*)(bb + (size_t)e * 1024 + t * 4);
    a0 += we * ((f0 - mean) * rstd * gv.x + bv.x);
    a1 += we * ((f1 - mean) * rstd * gv.y + bv.y);
    a2 += we * ((f2 - mean) * rstd * gv.z + bv.z);
    a3 += we * ((f3 - mean) * rstd * gv.w + bv.w);
    __syncthreads();
  }
  float4 r; r.x = a0; r.y = a1; r.z = a2; r.w = a3;
  *(float4*)(out + (size_t)tok * 1024 + t * 4) = r;
}

extern "C" void kernel_launch(void* const* d_in, const int* in_sizes, int n_in,
                              void* d_out, int out_size, void* d_ws, size_t ws_size,
                              hipStream_t stream)
{
  (void)in_sizes; (void)n_in; (void)out_size;
  const float* x        = (const float*)d_in[0];
  const float* gw       = (const float*)d_in[1];
  const float* gb       = (const float*)d_in[2];
  const float* enc_w1   = (const float*)d_in[3];
  const float* enc_b1   = (const float*)d_in[4];
  const float* enc_w2   = (const float*)d_in[5];
  const float* enc_b2   = (const float*)d_in[6];
  const float* enc_ln_g = (const float*)d_in[7];
  const float* enc_ln_b = (const float*)d_in[8];
  const float* ain_w    = (const float*)d_in[9];
  const float* ain_b    = (const float*)d_in[10];
  const float* aout_w   = (const float*)d_in[11];
  const float* aout_b   = (const float*)d_in[12];
  const float* w_ih     = (const float*)d_in[13];
  const float* w_hh     = (const float*)d_in[14];
  const float* b_ih     = (const float*)d_in[15];
  const float* b_hh     = (const float*)d_in[16];
  const float* exc_w1   = (const float*)d_in[17];
  const float* exc_b1   = (const float*)d_in[18];
  const float* exc_w2   = (const float*)d_in[19];
  const float* exc_b2   = (const float*)d_in[20];
  const float* opt_w1   = (const float*)d_in[21];
  const float* opt_b1   = (const float*)d_in[22];
  const float* opt_w2   = (const float*)d_in[23];
  const float* opt_b2   = (const float*)d_in[24];
  const float* dec_w1   = (const float*)d_in[25];
  const float* dec_b1   = (const float*)d_in[26];
  const float* dec_w2   = (const float*)d_in[27];
  const float* dec_b2   = (const float*)d_in[28];
  const float* dec_ln_g = (const float*)d_in[29];
  const float* dec_ln_b = (const float*)d_in[30];
  float* out = (float*)d_out;

  char* ws = (char*)d_ws;
  const size_t MB = 1ull << 20;
  u16* xbf  = (u16*)(ws);            // 2MB
  u16* h1   = (u16*)(ws + 2 * MB);   // 16MB
  u16* henc = (u16*)(ws + 18 * MB);  // 16MB
  u16* hbf  = (u16*)(ws + 34 * MB);  // 16MB
  u16* Qb   = (u16*)(ws + 2 * MB);   // reuse h1
  u16* Kb   = (u16*)(ws + 18 * MB);  // reuse henc
  u16* Vt   = (u16*)(ws + 50 * MB);  // 16MB
  u16* sp   = (u16*)(ws + 66 * MB);  // 32MB scores/P
  u16* abuf = (u16*)(ws + 2 * MB);   // reuse Qb
  u16* a_bf = (u16*)(ws + 18 * MB);  // reuse Kb
  u16* pre  = (u16*)(ws + 34 * MB);  // 64MB
  u16* Wf   = (u16*)(ws + 98 * MB);  // 128MB
  u16* mbuf = (u16*)(ws + 2 * MB);   // reuse abuf
  u16* t1   = (u16*)(ws + 18 * MB);  // reuse a_bf
  u16* excp = (u16*)(ws + 34 * MB);  // reuse pre (dead after recurrence)
  u16* t2   = (u16*)(ws + 50 * MB);
  u16* optp = (u16*)(ws + 66 * MB);
  u16* eo   = (u16*)(ws + 82 * MB);
  u16* t3   = (u16*)(ws + 18 * MB);  // reuse t1
  u16* decp = (u16*)(ws + 34 * MB);  // 8MB
  u16*   hbuf   = (u16*)(ws + 226 * MB);                    // 128KB: [2][32768]
  u32*   flags  = (u32*)(ws + 226 * MB + 128 * 1024);       // 16KB
  float* pooled = (float*)(ws + 226 * MB + 160 * 1024);     // 16KB
  float* wgate  = (float*)(ws + 226 * MB + 192 * 1024);     // 64B
  float* cbias  = (float*)(ws + 226 * MB + 224 * 1024);     // 128KB
  u16*   wbf    = (u16*)(ws + 227 * MB);                    // 120MB bf16 weight arena
  const bool jit = ws_size >= 356ull * MB;

  // bf16 arena element offsets (contiguous, 8-elem-chunk aligned)
  const size_t O_ENC_W1 = 0;          // 2048x1024 x4e
  const size_t O_ENC_W2 = 2097152 * 4ull;   // after enc_w1 (4*2M elems... see below)

  // Explicit cumulative offsets (elements):
  // enc_w1: 4*2048*1024  =  8,388,608
  // enc_w2: 4*2048*2048  = 16,777,216
  // ain_w : 4*6144*2048  = 50,331,648
  // aout_w: 4*2048*2048  = 16,777,216
  // w_ih  : 4*8192*2048  = 67,108,864
  // exc_w1/w2, opt_w1/w2, dec_w1: 16,777,216 each
  // dec_w2: 4*1024*2048  =  8,388,608
  const size_t oEncW1 = 0;
  const size_t oEncW2 = oEncW1 + 8388608ull;
  const size_t oAinW  = oEncW2 + 16777216ull;
  const size_t oAoutW = oAinW  + 50331648ull;
  const size_t oWih   = oAoutW + 16777216ull;
  const size_t oExcW1 = oWih   + 67108864ull;
  const size_t oExcW2 = oExcW1 + 16777216ull;
  const size_t oOptW1 = oExcW2 + 16777216ull;
  const size_t oOptW2 = oOptW1 + 16777216ull;
  const size_t oDecW1 = oOptW2 + 16777216ull;
  const size_t oDecW2 = oDecW1 + 16777216ull;
  (void)O_ENC_W1; (void)O_ENC_W2;

  // h0 = 0 (both hbuf halves) + flags = 0
  hipMemsetAsync(hbuf, 0, 128 * 1024 + 16 * 1024, stream);

  if (jit){
    // all conversions up-front, back-to-back (n8 = elems/8)
    convf2b<<<dim3(4096), dim3(256), 0, stream>>>(enc_w1, wbf + oEncW1, 1048576);
    convf2b<<<dim3(4096), dim3(256), 0, stream>>>(enc_w2, wbf + oEncW2, 2097152);
    convf2b<<<dim3(4096), dim3(256), 0, stream>>>(ain_w,  wbf + oAinW,  6291456);
    convf2b<<<dim3(4096), dim3(256), 0, stream>>>(aout_w, wbf + oAoutW, 2097152);
    convf2b<<<dim3(4096), dim3(256), 0, stream>>>(w_ih,   wbf + oWih,   8388608);
    convf2b<<<dim3(4096), dim3(256), 0, stream>>>(exc_w1, wbf + oExcW1, 2097152);
    convf2b<<<dim3(4096), dim3(256), 0, stream>>>(exc_w2, wbf + oExcW2, 2097152);
    convf2b<<<dim3(4096), dim3(256), 0, stream>>>(opt_w1, wbf + oOptW1, 2097152);
    convf2b<<<dim3(4096), dim3(256), 0, stream>>>(opt_w2, wbf + oOptW2, 2097152);
    convf2b<<<dim3(4096), dim3(256), 0, stream>>>(dec_w1, wbf + oDecW1, 2097152);
    convf2b<<<dim3(4096), dim3(256), 0, stream>>>(dec_w2, wbf + oDecW2, 1048576);
  }
  convert_x<<<dim3(512), dim3(256), 0, stream>>>(x, xbf);
  wf_convert<<<dim3(16384), dim3(256), 0, stream>>>(w_hh, Wf);
  comb_bias<<<dim3(32), dim3(256), 0, stream>>>(b_ih, b_hh, cbias);
  gate_pool<<<dim3(16), dim3(256), 0, stream>>>(x, pooled);
  gate_top2<<<dim3(1), dim3(256), 0, stream>>>(pooled, gw, gb, wgate);

  // enc: relu(x@W1^T+b1) @ W2^T + b2 -> LN
  if (jit){
    gemm_bt<1, 0, true, true, false><<<dim3(512), dim3(256), 0, stream>>>(
        xbf, wbf + oEncW1, h1, nullptr, nullptr, enc_b1, 2048, 1024, 1024, 1024,
        0LL, 2048LL * 1024, 1024LL * 2048, 2048, 8, 16, 1.f);
    gemm_bt<1, 0, true, false, false><<<dim3(512), dim3(256), 0, stream>>>(
        h1, wbf + oEncW2, henc, nullptr, nullptr, enc_b2, 2048, 2048, 2048, 2048,
        1024LL * 2048, 2048LL * 2048, 1024LL * 2048, 2048, 8, 16, 1.f);
  } else {
    gemm_bt<0, 0, true, true, false><<<dim3(512), dim3(256), 0, stream>>>(
        xbf, enc_w1, h1, nullptr, nullptr, enc_b1, 2048, 1024, 1024, 1024,
        0LL, 2048LL * 1024, 1024LL * 2048, 2048, 8, 16, 1.f);
    gemm_bt<0, 0, true, false, false><<<dim3(512), dim3(256), 0, stream>>>(
        h1, enc_w2, henc, nullptr, nullptr, enc_b2, 2048, 2048, 2048, 2048,
        1024LL * 2048, 2048LL * 2048, 1024LL * 2048, 2048, 8, 16, 1.f);
  }
  ln2048<<<dim3(4096), dim3(256), 0, stream>>>(henc, hbf, enc_ln_g, enc_ln_b);

  // attention
  if (jit){
    gemm_bt<1, 1, true, false, false><<<dim3(1536), dim3(256), 0, stream>>>(
        hbf, wbf + oAinW, Qb, Kb, Vt, ain_b, 6144, 2048, 2048, 2048,
        1024LL * 2048, 6144LL * 2048, 0LL, 6144, 8, 48, 1.f);
  } else {
    gemm_bt<0, 1, true, false, false><<<dim3(1536), dim3(256), 0, stream>>>(
        hbf, ain_w, Qb, Kb, Vt, ain_b, 6144, 2048, 2048, 2048,
        1024LL * 2048, 6144LL * 2048, 0LL, 6144, 8, 48, 1.f);
  }
  gemm_bt<1, 0, false, false, true><<<dim3(1024), dim3(256), 0, stream>>>(
      Qb, Kb, sp, nullptr, nullptr, nullptr, 256, 128, 128, 128,
      32768LL, 32768LL, 65536LL, 0, 2, 2, 0.08838834764831845f);
  softmax256<<<dim3(16384), dim3(256), 0, stream>>>(sp);
  gemm_bt<1, 2, false, false, false><<<dim3(512), dim3(256), 0, stream>>>(
      sp, Vt, abuf, nullptr, nullptr, nullptr, 128, 256, 256, 256,
      65536LL, 32768LL, 0LL, 0, 2, 1, 1.f);
  if (jit){
    gemm_bt<1, 0, true, false, false><<<dim3(512), dim3(256), 0, stream>>>(
        abuf, wbf + oAoutW, a_bf, nullptr, nullptr, aout_b, 2048, 2048, 2048, 2048,
        1024LL * 2048, 2048LL * 2048, 1024LL * 2048, 2048, 8, 16, 1.f);
    gemm_bt<1, 0, true, false, false><<<dim3(2048), dim3(256), 0, stream>>>(
        a_bf, wbf + oWih, pre, nullptr, nullptr, cbias, 8192, 2048, 2048, 2048,
        1024LL * 2048, 8192LL * 2048, 1024LL * 8192, 8192, 8, 64, 1.f);
  } else {
    gemm_bt<0, 0, true, false, false><<<dim3(512), dim3(256), 0, stream>>>(
        abuf, aout_w, a_bf, nullptr, nullptr, aout_b, 2048, 2048, 2048, 2048,
        1024LL * 2048, 2048LL * 2048, 1024LL * 2048, 2048, 8, 16, 1.f);
    gemm_bt<0, 0, true, false, false><<<dim3(2048), dim3(256), 0, stream>>>(
        a_bf, w_ih, pre, nullptr, nullptr, cbias, 8192, 2048, 2048, 2048,
        1024LL * 2048, 8192LL * 2048, 1024LL * 8192, 8192, 8, 64, 1.f);
  }
  lstm_persist<<<dim3(256), dim3(512), 0, stream>>>(Wf, pre, hbuf, mbuf, flags);

  // exc / opt / dec
  if (jit){
    gemm_bt<1, 0, true, true, false><<<dim3(512), dim3(256), 0, stream>>>(
        mbuf, wbf + oExcW1, t1, nullptr, nullptr, exc_b1, 2048, 2048, 2048, 2048,
        1024LL * 2048, 2048LL * 2048, 1024LL * 2048, 2048, 8, 16, 1.f);
    gemm_bt<1, 0, true, false, false><<<dim3(512), dim3(256), 0, stream>>>(
        t1, wbf + oExcW2, excp, nullptr, nullptr, exc_b2, 2048, 2048, 2048, 2048,
        1024LL * 2048, 2048LL * 2048, 1024LL * 2048, 2048, 8, 16, 1.f);
    gemm_bt<1, 0, true, true, false><<<dim3(512), dim3(256), 0, stream>>>(
        mbuf, wbf + oOptW1, t2, nullptr, nullptr, opt_b1, 2048, 2048, 2048, 2048,
        1024LL * 2048, 2048LL * 2048, 1024LL * 2048, 2048, 8, 16, 1.f);
    gemm_bt<1, 0, true, false, false><<<dim3(512), dim3(256), 0, stream>>>(
        t2, wbf + oOptW2, optp, nullptr, nullptr, opt_b2, 2048, 2048, 2048, 2048,
        1024LL * 2048, 2048LL * 2048, 1024LL * 2048, 2048, 8, 16, 1.f);
  } else {
    gemm_bt<0, 0, true, true, false><<<dim3(512), dim3(256), 0, stream>>>(
        mbuf, exc_w1, t1, nullptr, nullptr, exc_b1, 2048, 2048, 2048, 2048,
        1024LL * 2048, 2048LL * 2048, 1024LL * 2048, 2048, 8, 16, 1.f);
    gemm_bt<0, 0, true, false, false><<<dim3(512), dim3(256), 0, stream>>>(
        t1, exc_w2, excp, nullptr, nullptr, exc_b2, 2048, 2048, 2048, 2048,
        1024LL * 2048, 2048LL * 2048, 1024LL * 2048, 2048, 8, 16, 1.f);
    gemm_bt<0, 0, true, true, false><<<dim3(512), dim3(256), 0, stream>>>(
        mbuf, opt_w1, t2, nullptr, nullptr, opt_b1, 2048, 2048, 2048, 2048,
        1024LL * 2048, 2048LL * 2048, 1024LL * 2048, 2048, 8, 16, 1.f);
    gemm_bt<0, 0, true, false, false><<<dim3(512), dim3(256), 0, stream>>>(
        t2, opt_w2, optp, nullptr, nullptr, opt_b2, 2048, 2048, 2048, 2048,
        1024LL * 2048, 2048LL * 2048, 1024LL * 2048, 2048, 8, 16, 1.f);
  }
  eo_kernel<<<dim3(4096), dim3(256), 0, stream>>>(excp, optp, eo);
  if (jit){
    gemm_bt<1, 0, true, true, false><<<dim3(512), dim3(256), 0, stream>>>(
        eo, wbf + oDecW1, t3, nullptr, nullptr, dec_b1, 2048, 2048, 2048, 2048,
        1024LL * 2048, 2048LL * 2048, 1024LL * 2048, 2048, 8, 16, 1.f);
    gemm_bt<1, 0, true, false, false><<<dim3(256), dim3(256), 0, stream>>>(
        t3, wbf + oDecW2, decp, nullptr, nullptr, dec_b2, 1024, 2048, 2048, 2048,
        1024LL * 2048, 1024LL * 2048, 1024LL * 1024, 1024, 8, 8, 1.f);
  } else {
    gemm_bt<0, 0, true, true, false><<<dim3(512), dim3(256), 0, stream>>>(
        eo, dec_w1, t3, nullptr, nullptr, dec_b1, 2048, 2048, 2048, 2048,
        1024LL * 2048, 2048LL * 2048, 1024LL * 2048, 2048, 8, 16, 1.f);
    gemm_bt<0, 0, true, false, false><<<dim3(256), dim3(256), 0, stream>>>(
        t3, dec_w2, decp, nullptr, nullptr, dec_b2, 1024, 2048, 2048, 2048,
        1024LL * 2048, 1024LL * 2048, 1024LL * 1024, 1024, 8, 8, 1.f);
  }

  final_combine<<<dim3(1024), dim3(256), 0, stream>>>(decp, wgate, dec_ln_g, dec_ln_b, out);
}

// Round 16
// 2109.582 us; speedup vs baseline: 1.0491x; 1.0491x over previous
//
#include <hip/hip_runtime.h>
#include <hip/hip_bf16.h>

// UltimateExcellencePiMoE on MI355X.  R16 == R11 (best verified: 2113us).
// B=4, S=256, D=1024, E=2048, H=16, HD=128, NE=4, K(topk)=2.
// GEMM: single-buffer BK=64 tile 128x128, global_load_lds(16B) staging.
// JIT conv: single reused wslot immediately before each GEMM (acts as L2
// prefetch for the GEMM's weight reads -- R15 showed up-front arena is
// ~100us WORSE due to L2 eviction). LSTM: R8-verified persistent kernel.

typedef unsigned short u16;
typedef unsigned int u32;
typedef unsigned long long u64;
typedef __attribute__((ext_vector_type(8))) short short8;
typedef __attribute__((ext_vector_type(4))) float f32x4;

#define DEV static __device__ __forceinline__

DEV u16 f2bf(float f){ u32 u = __float_as_uint(f); u += 0x7fffu + ((u >> 16) & 1u); return (u16)(u >> 16); }
DEV float bf2f(u16 s){ return __uint_as_float(((u32)s) << 16); }
DEV u32 pk2(float a, float b){ return (u32)f2bf(a) | ((u32)f2bf(b) << 16); }
DEV float sigf(float x){ return 1.f / (1.f + __expf(-x)); }
DEV float sig_fast(float x){ return __builtin_amdgcn_rcpf(1.f + __expf(-x)); }
DEV float tanh_fast(float x){
  float ax = fabsf(x);
  float t = __expf(-2.f * ax);
  float r = (1.f - t) * __builtin_amdgcn_rcpf(1.f + t);
  return copysignf(r, x);
}

// async global->LDS, 16B per lane; LDS dest = wave-uniform base + lane*16.
DEV void gld16(u16* lds, const u16* g){
  __builtin_amdgcn_global_load_lds((const __attribute__((address_space(1))) u32*)g,
                                   (__attribute__((address_space(3))) u32*)lds, 16, 0, 0);
}

// 2-stat block reduction, assumes 256 threads (4 waves). red: float[16] LDS.
DEV void bred2(float& s, float& ss, float* red){
  #pragma unroll
  for (int o = 32; o; o >>= 1){ s += __shfl_xor(s, o); ss += __shfl_xor(ss, o); }
  int wv = threadIdx.x >> 6, ln = threadIdx.x & 63;
  if (ln == 0){ red[wv] = s; red[8 + wv] = ss; }
  __syncthreads();
  s = red[0] + red[1] + red[2] + red[3];
  ss = red[8] + red[9] + red[10] + red[11];
}

// ---------------- generic batched GEMM: C = act(scale * (A @ B^T) + bias) ----
// Tile 128x128, BK=64 stored as two stacked 32-col halves (4096 elems each):
// elem (row, col) -> [ (col>>5)*4096 + row*32 + (col&31) ].
// BMODE 1: A,B bf16 via global_load_lds (linear dest = chunk*8).
// BMODE 0: A via global_load_lds; B fp32 converted in-kernel (fallback).
template<int BMODE, int SC, bool BIAS, bool RELU, bool SCALE>
__global__ void __launch_bounds__(256, 2) gemm_bt(
    const u16* __restrict__ A, const void* __restrict__ Bv,
    u16* __restrict__ C0, u16* __restrict__ C1, u16* __restrict__ C2,
    const float* __restrict__ bias,
    int N, int K, int lda, int ldb,
    long long sA, long long sB, long long sC, int sBias,
    int nbm, int nbn, float scale)
{
  __shared__ u16 As[8192];   // 16 KB: [half2][128][32]
  __shared__ u16 Bs[8192];   // 16 KB
  int bid = blockIdx.x;
  int per = nbm * nbn;
  int batch = bid / per;
  int rem = bid - batch * per;
  int bm = rem % nbm, bn = rem / nbm;
  int t = threadIdx.x;
  int wave = t >> 6, lane = t & 63, fm = lane & 15, kg = lane >> 4;
  int wm = (wave >> 1) * 64, wn = (wave & 1) * 64;
  const u16* Ab = A + (size_t)batch * sA + (size_t)(bm * 128) * lda;
  const u16* Bb16 = nullptr;
  if constexpr (BMODE == 1)
    Bb16 = (const u16*)Bv + (size_t)batch * sB + (size_t)(bn * 128) * ldb;
  int aoff[4], boff[4];
  #pragma unroll
  for (int mi = 0; mi < 4; ++mi) aoff[mi] = (wm + mi * 16 + fm) * 32 + kg * 8;
  #pragma unroll
  for (int ni = 0; ni < 4; ++ni) boff[ni] = (wn + ni * 16 + fm) * 32 + kg * 8;
  // staging chunk -> (row, gcol): c in [0,1024); rr=(c>>2)&127,
  // gcol = (c>>9)*32 + (c&3)*8; dest = c*8 (linear per wave).
  int rr_[4], gc_[4];
  #pragma unroll
  for (int q = 0; q < 4; ++q){
    int c = q * 256 + t;
    rr_[q] = (c >> 2) & 127;
    gc_[q] = (c >> 9) * 32 + (c & 3) * 8;
  }
  f32x4 zero = {0.f, 0.f, 0.f, 0.f};
  f32x4 acc[4][4];
  #pragma unroll
  for (int i = 0; i < 4; ++i)
    #pragma unroll
    for (int j = 0; j < 4; ++j) acc[i][j] = zero;
  int nk = K >> 6;
  for (int ks = 0; ks < nk; ++ks){
    int k0 = ks << 6;
    if constexpr (BMODE == 1){
      #pragma unroll
      for (int q = 0; q < 4; ++q){
        int c = q * 256 + t;
        gld16(&As[c * 8], Ab + (size_t)rr_[q] * lda + k0 + gc_[q]);
        gld16(&Bs[c * 8], Bb16 + (size_t)rr_[q] * ldb + k0 + gc_[q]);
      }
    } else {
      #pragma unroll
      for (int q = 0; q < 4; ++q){
        int c = q * 256 + t;
        gld16(&As[c * 8], Ab + (size_t)rr_[q] * lda + k0 + gc_[q]);
      }
      int n = t >> 1, half = t & 1;
      const float* Bb = (const float*)Bv + (size_t)batch * sB + (size_t)(bn * 128 + n) * ldb + k0 + half * 32;
      u16* bd = &Bs[half * 4096 + n * 32];
      #pragma unroll
      for (int j = 0; j < 4; ++j){
        float4 fa = *(const float4*)(Bb + j * 8);
        float4 fb = *(const float4*)(Bb + j * 8 + 4);
        uint4 o;
        o.x = pk2(fa.x, fa.y); o.y = pk2(fa.z, fa.w);
        o.z = pk2(fb.x, fb.y); o.w = pk2(fb.z, fb.w);
        *(uint4*)(bd + j * 8) = o;
      }
    }
    __syncthreads();
    #pragma unroll
    for (int ki = 0; ki < 2; ++ki){
      short8 afr[4], bfr[4];
      #pragma unroll
      for (int mi = 0; mi < 4; ++mi) afr[mi] = *(const short8*)&As[ki * 4096 + aoff[mi]];
      #pragma unroll
      for (int ni = 0; ni < 4; ++ni) bfr[ni] = *(const short8*)&Bs[ki * 4096 + boff[ni]];
      #pragma unroll
      for (int mi = 0; mi < 4; ++mi)
        #pragma unroll
        for (int ni = 0; ni < 4; ++ni)
          acc[mi][ni] = __builtin_amdgcn_mfma_f32_16x16x32_bf16(afr[mi], bfr[ni], acc[mi][ni], 0, 0, 0);
    }
    __syncthreads();
  }
  #pragma unroll
  for (int mi = 0; mi < 4; ++mi){
    #pragma unroll
    for (int ni = 0; ni < 4; ++ni){
      f32x4 v = acc[mi][ni];
      int gm0 = bm * 128 + wm + mi * 16 + kg * 4;
      int gn = bn * 128 + wn + ni * 16 + fm;
      float bv = 0.f;
      if constexpr (BIAS) bv = bias[(size_t)batch * sBias + gn];
      #pragma unroll
      for (int jj = 0; jj < 4; ++jj){
        float xv = v[jj];
        if constexpr (SCALE) xv *= scale;
        if constexpr (BIAS) xv += bv;
        if constexpr (RELU) xv = fmaxf(xv, 0.f);
        int gm = gm0 + jj;
        u16 ov = f2bf(xv);
        if constexpr (SC == 0){
          C0[(size_t)batch * sC + (size_t)gm * N + gn] = ov;
        } else if constexpr (SC == 1){
          int which = gn >> 11, hh = (gn >> 7) & 15, d = gn & 127;
          int b_ = gm >> 8, s_ = gm & 255;
          size_t hb = ((size_t)batch * 4 + b_) * 16 + hh;
          if (which == 0)      C0[(hb * 256 + s_) * 128 + d] = ov;       // Q[e,b,h,s,d]
          else if (which == 1) C1[(hb * 256 + s_) * 128 + d] = ov;       // K[e,b,h,s,d]
          else                 C2[(hb * 128 + d) * 256 + s_] = ov;       // V^T[e,b,h,d,s]
        } else {
          int e_ = batch >> 6, b_ = (batch >> 4) & 3, hh = batch & 15;
          C0[(((size_t)e_ * 4 + b_) * 256 + gm) * 2048 + hh * 128 + gn] = ov;
        }
      }
    }
  }
}

// ---------------- small kernels -------------------------------------------
__global__ void __launch_bounds__(256, 4) convf2b(const float* __restrict__ src, u16* __restrict__ dst, int n8){
  int stride = gridDim.x * 256;
  for (int i = blockIdx.x * 256 + threadIdx.x; i < n8; i += stride){
    float4 a = *(const float4*)(src + (size_t)i * 8);
    float4 b = *(const float4*)(src + (size_t)i * 8 + 4);
    uint4 o;
    o.x = pk2(a.x, a.y); o.y = pk2(a.z, a.w); o.z = pk2(b.x, b.y); o.w = pk2(b.z, b.w);
    *(uint4*)(dst + (size_t)i * 8) = o;
  }
}

__global__ void __launch_bounds__(256, 4) convert_x(const float* __restrict__ x, u16* __restrict__ xb){
  int idx = blockIdx.x * 256 + threadIdx.x;
  float4 a = *(const float4*)(x + (size_t)idx * 8);
  float4 b = *(const float4*)(x + (size_t)idx * 8 + 4);
  uint4 o;
  o.x = pk2(a.x, a.y); o.y = pk2(a.z, a.w); o.z = pk2(b.x, b.y); o.w = pk2(b.z, b.w);
  *(uint4*)(xb + (size_t)idx * 8) = o;
}

__global__ void __launch_bounds__(256, 4) comb_bias(const float* __restrict__ a, const float* __restrict__ b, float* __restrict__ o){
  int idx = blockIdx.x * 256 + threadIdx.x;
  float4 va = *(const float4*)(a + (size_t)idx * 4);
  float4 vb = *(const float4*)(b + (size_t)idx * 4);
  float4 r; r.x = va.x + vb.x; r.y = va.y + vb.y; r.z = va.z + vb.z; r.w = va.w + vb.w;
  *(float4*)(o + (size_t)idx * 4) = r;
}

__global__ void __launch_bounds__(256, 4) gate_pool(const float* __restrict__ x, float* __restrict__ pooled){
  int id = blockIdx.x * 256 + threadIdx.x;
  int b = id >> 10, d = id & 1023;
  const float* p = x + (size_t)b * 262144 + d;
  float s = 0.f;
  for (int si = 0; si < 256; ++si) s += p[si * 1024];
  pooled[id] = s * (1.f / 256.f);
}

__global__ void __launch_bounds__(256, 2) gate_top2(const float* __restrict__ pooled,
    const float* __restrict__ gw, const float* __restrict__ gb, float* __restrict__ wout)
{
  __shared__ float part[16][16];
  __shared__ float lg[4][4];
  int t = threadIdx.x;
  int pair = t >> 4, l = t & 15;
  int b = pair >> 2, e = pair & 3;
  float s = 0.f;
  for (int d = l; d < 1024; d += 16) s += pooled[b * 1024 + d] * gw[d * 4 + e];
  part[pair][l] = s;
  __syncthreads();
  if (t < 16){
    float v = 0.f;
    #pragma unroll
    for (int i = 0; i < 16; ++i) v += part[t][i];
    lg[t >> 2][t & 3] = v + gb[t & 3];
  }
  __syncthreads();
  if (t < 4){
    float p[4];
    float mx = -1e30f;
    for (int i = 0; i < 4; ++i) mx = fmaxf(mx, lg[t][i]);
    float sum = 0.f;
    for (int i = 0; i < 4; ++i){ p[i] = expf(lg[t][i] - mx); sum += p[i]; }
    for (int i = 0; i < 4; ++i) p[i] /= sum;
    int i1 = 0;
    for (int i = 1; i < 4; ++i) if (p[i] > p[i1]) i1 = i;
    int i2 = (i1 == 0) ? 1 : 0;
    for (int i = 0; i < 4; ++i) if (i != i1 && p[i] > p[i2]) i2 = i;
    float den = p[i1] + p[i2];
    float w4[4] = {0.f, 0.f, 0.f, 0.f};
    w4[i1] = p[i1] / den; w4[i2] = p[i2] / den;
    for (int i = 0; i < 4; ++i) wout[t * 4 + i] = w4[i];
  }
}

__global__ void __launch_bounds__(256, 4) ln2048(const u16* __restrict__ in, u16* __restrict__ out,
                                                 const float* __restrict__ gg, const float* __restrict__ bb)
{
  __shared__ float red[16];
  int row = blockIdx.x, e = row >> 10, t = threadIdx.x;
  uint4 v = *(const uint4*)(in + (size_t)row * 2048 + t * 8);
  float f[8] = { bf2f(v.x & 0xffff), bf2f(v.x >> 16), bf2f(v.y & 0xffff), bf2f(v.y >> 16),
                 bf2f(v.z & 0xffff), bf2f(v.z >> 16), bf2f(v.w & 0xffff), bf2f(v.w >> 16) };
  float s = 0.f, ss = 0.f;
  #pragma unroll
  for (int i = 0; i < 8; ++i){ s += f[i]; ss += f[i] * f[i]; }
  bred2(s, ss, red);
  float mean = s * (1.f / 2048.f);
  float var = ss * (1.f / 2048.f) - mean * mean;
  float rstd = rsqrtf(var + 1e-5f);
  const float* g4 = gg + (size_t)e * 2048 + t * 8;
  const float* b4 = bb + (size_t)e * 2048 + t * 8;
  float4 ga = *(const float4*)g4, gb2 = *(const float4*)(g4 + 4);
  float4 ba = *(const float4*)b4, bb2 = *(const float4*)(b4 + 4);
  float r[8];
  r[0] = (f[0] - mean) * rstd * ga.x + ba.x; r[1] = (f[1] - mean) * rstd * ga.y + ba.y;
  r[2] = (f[2] - mean) * rstd * ga.z + ba.z; r[3] = (f[3] - mean) * rstd * ga.w + ba.w;
  r[4] = (f[4] - mean) * rstd * gb2.x + bb2.x; r[5] = (f[5] - mean) * rstd * gb2.y + bb2.y;
  r[6] = (f[6] - mean) * rstd * gb2.z + bb2.z; r[7] = (f[7] - mean) * rstd * gb2.w + bb2.w;
  uint4 o; o.x = pk2(r[0], r[1]); o.y = pk2(r[2], r[3]); o.z = pk2(r[4], r[5]); o.w = pk2(r[6], r[7]);
  *(uint4*)(out + (size_t)row * 2048 + t * 8) = o;
}

__global__ void __launch_bounds__(256, 4) softmax256(u16* __restrict__ sp){
  int row = blockIdx.x * 4 + (threadIdx.x >> 6);
  int ln = threadIdx.x & 63;
  u16* p = sp + (size_t)row * 256 + ln * 4;
  uint2 v = *(const uint2*)p;
  float f0 = bf2f(v.x & 0xffff), f1 = bf2f(v.x >> 16), f2 = bf2f(v.y & 0xffff), f3 = bf2f(v.y >> 16);
  float mx = fmaxf(fmaxf(f0, f1), fmaxf(f2, f3));
  #pragma unroll
  for (int o = 32; o; o >>= 1) mx = fmaxf(mx, __shfl_xor(mx, o));
  float e0 = __expf(f0 - mx), e1 = __expf(f1 - mx), e2 = __expf(f2 - mx), e3 = __expf(f3 - mx);
  float s = e0 + e1 + e2 + e3;
  #pragma unroll
  for (int o = 32; o; o >>= 1) s += __shfl_xor(s, o);
  float inv = 1.f / s;
  uint2 ov; ov.x = pk2(e0 * inv, e1 * inv); ov.y = pk2(e2 * inv, e3 * inv);
  *(uint2*)p = ov;
}

// W_hh (e,4E,E) fp32 -> per-wave MFMA B-fragment layout Wf[e][nt][kt][lane][8] bf16.
__global__ void __launch_bounds__(256, 2) wf_convert(const float* __restrict__ whh, u16* __restrict__ Wf){
  __shared__ float ls[16 * 260];
  int bid = blockIdx.x;
  int e = bid >> 12, nt = (bid >> 3) & 511, ktg = bid & 7;
  int t = threadIdx.x;
  const float* src = whh + ((size_t)e * 8192 + nt * 16) * 2048 + ktg * 256;
  #pragma unroll
  for (int it = 0; it < 4; ++it){
    int idx = it * 256 + t;
    int r = idx >> 6, f4 = (idx & 63) * 4;
    *(float4*)&ls[r * 260 + f4] = *(const float4*)(src + (size_t)r * 2048 + f4);
  }
  __syncthreads();
  #pragma unroll
  for (int it = 0; it < 2; ++it){
    int idx = it * 256 + t;
    int ktl = idx >> 6, lane = idx & 63;
    int r = lane & 15, kloc = ktl * 32 + (lane >> 4) * 8;
    float4 va = *(const float4*)&ls[r * 260 + kloc];
    float4 vb = *(const float4*)&ls[r * 260 + kloc + 4];
    uint4 o; o.x = pk2(va.x, va.y); o.y = pk2(va.z, va.w); o.z = pk2(vb.x, vb.y); o.w = pk2(vb.z, vb.w);
    size_t chunk = ((size_t)(e * 512 + nt) * 64 + (ktg * 8 + ktl)) * 64 + lane;
    *(uint4*)(Wf + chunk * 8) = o;
  }
}

// ---------------- persistent LSTM recurrence --------------------------------
// grid = 256 blocks (1/CU via ~147KB LDS) x 512 threads (8 waves).
// R8-verified tail (976us) with s_sleep poll.
__global__ void __launch_bounds__(512, 2) lstm_persist(
    const u16* __restrict__ Wf, const u16* __restrict__ pre,
    u16* hbuf,                 // [2][e(4)][b(4)][2048] bf16
    u16* __restrict__ mout,    // [(e*4+b)*256+step][2048] bf16
    u32* flags)                // [4][64][16] u32 (64B stride per block)
{
  __shared__ u16 pinW[8 * 16 * 512];      // 128 KB
  __shared__ u16 hA[64 * 136];            // 17 KB: [kt64][kg4][r4][8] +pad
  __shared__ float g_s[8][16][4];         // 2 KB
  int blk = blockIdx.x;
  int e = blk & 3, be = blk >> 2;         // XCD-local expert mapping
  int jb = be * 32;
  int t = threadIdx.x;
  int wave = t >> 6, lane = t & 63;
  int fm = lane & 15, kg = lane >> 4;
  int gate = wave >> 1, half = wave & 1;
  int nt = gate * 128 + (jb >> 4) + half;
  const u16* wp = Wf + (((size_t)(e * 512 + nt) * 64) * 64 + lane) * 8;
  #pragma unroll
  for (int kt = 0; kt < 16; ++kt)
    *(uint4*)&pinW[(wave * 16 + kt) * 512 + lane * 8] = *(const uint4*)(wp + (size_t)kt * 512);
  short8 wreg[40];
  #pragma unroll
  for (int i = 0; i < 40; ++i)
    wreg[i] = *(const short8*)(wp + (size_t)(16 + i) * 512);
  const u16* wps = wp + (size_t)56 * 512;
  const u16* arow = &hA[kg * 32 + (fm & 3) * 8];   // duplicate-row A address
  int b_ = t >> 4, jp = t & 15;                    // epilogue mapping (t<64)
  int w0 = jp >> 3, j0 = jp * 2, c0 = j0 & 15, c1 = c0 + 1;
  float creg0 = 0.f, creg1 = 0.f;
  u32* myflags = flags + e * 1024;                 // 64 blocks * 16 u32
  size_t moutbase = ((size_t)(e * 4 + b_) * 256) * 2048 + jb + j0;
  for (int step = 0; step < 256; ++step){
    int par = step & 1;
    u32 pi = 0, pf = 0, pg = 0, po = 0;
    if (t < 64){
      size_t prebase = ((size_t)(e * 4 + b_) * 256 + step) * 8192 + jb + j0;
      pi = *(const u32*)(pre + prebase);
      pf = *(const u32*)(pre + prebase + 2048);
      pg = *(const u32*)(pre + prebase + 4096);
      po = *(const u32*)(pre + prebase + 6144);
    }
    const u16* hsrc = hbuf + par * 32768 + e * 8192;
    #pragma unroll
    for (int it = 0; it < 4; ++it){
      int c8 = it * 512 + t;
      int r = c8 >> 9, w4 = c8 & 511;
      u64 v = __hip_atomic_load((const u64*)(hsrc + r * 2048 + w4 * 4),
                                __ATOMIC_RELAXED, __HIP_MEMORY_SCOPE_AGENT);
      int di = (w4 >> 3) * 136 + ((w4 >> 1) & 3) * 32 + r * 8 + (w4 & 1) * 4;
      *(u64*)&hA[di] = v;
    }
    __syncthreads();                      // sync1: hA ready
    short8 wtmp[8];
    #pragma unroll
    for (int i = 0; i < 8; ++i)
      wtmp[i] = *(const short8*)(wps + (size_t)i * 512);
    f32x4 acc[4];
    #pragma unroll
    for (int i = 0; i < 4; ++i) acc[i] = (f32x4){0.f, 0.f, 0.f, 0.f};
    #pragma unroll
    for (int kt = 0; kt < 16; ++kt){
      short8 a = *(const short8*)(arow + kt * 136);
      short8 b = *(const short8*)&pinW[(wave * 16 + kt) * 512 + lane * 8];
      acc[kt & 3] = __builtin_amdgcn_mfma_f32_16x16x32_bf16(a, b, acc[kt & 3], 0, 0, 0);
    }
    #pragma unroll
    for (int i = 0; i < 40; ++i){
      short8 a = *(const short8*)(arow + (16 + i) * 136);
      acc[i & 3] = __builtin_amdgcn_mfma_f32_16x16x32_bf16(a, wreg[i], acc[i & 3], 0, 0, 0);
    }
    #pragma unroll
    for (int i = 0; i < 8; ++i){
      short8 a = *(const short8*)(arow + (56 + i) * 136);
      acc[i & 3] = __builtin_amdgcn_mfma_f32_16x16x32_bf16(a, wtmp[i], acc[i & 3], 0, 0, 0);
    }
    f32x4 accs = (acc[0] + acc[1]) + (acc[2] + acc[3]);
    if (lane < 16){
      #pragma unroll
      for (int jj = 0; jj < 4; ++jj) g_s[wave][lane][jj] = accs[jj];
    }
    __syncthreads();                      // sync2: g_s ready
    if (t < 64){
      float gi0 = g_s[0 + w0][c0][b_] + bf2f(pi & 0xffff), gi1 = g_s[0 + w0][c1][b_] + bf2f(pi >> 16);
      float gf0 = g_s[2 + w0][c0][b_] + bf2f(pf & 0xffff), gf1 = g_s[2 + w0][c1][b_] + bf2f(pf >> 16);
      float gg0 = g_s[4 + w0][c0][b_] + bf2f(pg & 0xffff), gg1 = g_s[4 + w0][c1][b_] + bf2f(pg >> 16);
      float go0 = g_s[6 + w0][c0][b_] + bf2f(po & 0xffff), go1 = g_s[6 + w0][c1][b_] + bf2f(po >> 16);
      float c0v = sig_fast(gf0) * creg0 + sig_fast(gi0) * tanh_fast(gg0);
      float c1v = sig_fast(gf1) * creg1 + sig_fast(gi1) * tanh_fast(gg1);
      float h0 = sig_fast(go0) * tanh_fast(c0v);
      float h1 = sig_fast(go1) * tanh_fast(c1v);
      creg0 = c0v; creg1 = c1v;
      u32 hv = pk2(h0, h1);
      __hip_atomic_store((u32*)(hbuf + (par ^ 1) * 32768 + e * 8192 + b_ * 2048 + jb + j0), hv,
                         __ATOMIC_RELAXED, __HIP_MEMORY_SCOPE_AGENT);
      *(u32*)(mout + moutbase + (size_t)step * 2048) = hv;   // ack overlaps h ack
    }
    __syncthreads();  // sync3: drains h (coherence) + mout (HBM) concurrently
    if (step < 255 && t < 64){
      if (t == 0)
        __hip_atomic_store(&myflags[be * 16], (u32)(step + 1), __ATOMIC_RELAXED, __HIP_MEMORY_SCOPE_AGENT);
      u32 fuel = 0;
      do {
        u32 f = __hip_atomic_load(&myflags[t * 16], __ATOMIC_RELAXED, __HIP_MEMORY_SCOPE_AGENT);
        if (!__any(f < (u32)(step + 1))) break;
        __builtin_amdgcn_s_sleep(1);
      } while (++fuel < (1u << 22));   // bounded: degrades instead of hanging
    }
    __syncthreads();  // loop-end: nothing outstanding -> cheap
  }
}

__global__ void __launch_bounds__(256, 4) eo_kernel(const u16* __restrict__ ep, const u16* __restrict__ op, u16* __restrict__ eo){
  int idx = blockIdx.x * 256 + threadIdx.x;
  uint4 ev = *(const uint4*)(ep + (size_t)idx * 8);
  uint4 ov = *(const uint4*)(op + (size_t)idx * 8);
  u32 e4[4] = {ev.x, ev.y, ev.z, ev.w};
  u32 o4[4] = {ov.x, ov.y, ov.z, ov.w};
  uint4 r;
  u32* rp = (u32*)&r;
  #pragma unroll
  for (int q = 0; q < 4; ++q){
    float a0 = sigf(bf2f(e4[q] & 0xffff)) * tanhf(bf2f(o4[q] & 0xffff));
    float a1 = sigf(bf2f(e4[q] >> 16)) * tanhf(bf2f(o4[q] >> 16));
    rp[q] = pk2(a0, a1);
  }
  *(uint4*)(eo + (size_t)idx * 8) = r;
}

__global__ void __launch_bounds__(256, 2) final_combine(const u16* __restrict__ decp, const float* __restrict__ wg,
    const float* __restrict__ gg, const float* __restrict__ bb, float* __restrict__ out)
{
  __shared__ float red[16];
  int tok = blockIdx.x;
  int b = tok >> 8;
  int t = threadIdx.x;
  float a0 = 0.f, a1 = 0.f, a2 = 0.f, a3 = 0.f;
  for (int e = 0; e < 4; ++e){
    const u16* p = decp + ((size_t)e * 1024 + tok) * 1024 + t * 4;
    uint2 v = *(const uint2*)p;
    float f0 = bf2f(v.x & 0xffff), f1 = bf2f(v.x >> 16), f2 = bf2f(v.y & 0xffff), f3 = bf2f(v.y >> 16);
    float s = f0 + f1 + f2 + f3;
    float ss = f0 * f0 + f1 * f1 + f2 * f2 + f3 * f3;
    bred2(s, ss, red);
    float mean = s * (1.f / 1024.f);
    float var = ss * (1.f / 1024.f) - mean * mean;
    float rstd = rsqrtf(var + 1e-5f);
    float we = wg[b * 4 + e];
    float4 gv = *(const float4*)(gg + (size_t)e * 1024 + t * 4);
    float4 bv = *(const float4*)(bb + (size_t)e * 1024 + t * 4);
    a0 += we * ((f0 - mean) * rstd * gv.x + bv.x);
    a1 += we * ((f1 - mean) * rstd * gv.y + bv.y);
    a2 += we * ((f2 - mean) * rstd * gv.z + bv.z);
    a3 += we * ((f3 - mean) * rstd * gv.w + bv.w);
    __syncthreads();
  }
  float4 r; r.x = a0; r.y = a1; r.z = a2; r.w = a3;
  *(float4*)(out + (size_t)tok * 1024 + t * 4) = r;
}

extern "C" void kernel_launch(void* const* d_in, const int* in_sizes, int n_in,
                              void* d_out, int out_size, void* d_ws, size_t ws_size,
                              hipStream_t stream)
{
  (void)in_sizes; (void)n_in; (void)out_size;
  const float* x        = (const float*)d_in[0];
  const float* gw       = (const float*)d_in[1];
  const float* gb       = (const float*)d_in[2];
  const float* enc_w1   = (const float*)d_in[3];
  const float* enc_b1   = (const float*)d_in[4];
  const float* enc_w2   = (const float*)d_in[5];
  const float* enc_b2   = (const float*)d_in[6];
  const float* enc_ln_g = (const float*)d_in[7];
  const float* enc_ln_b = (const float*)d_in[8];
  const float* ain_w    = (const float*)d_in[9];
  const float* ain_b    = (const float*)d_in[10];
  const float* aout_w   = (const float*)d_in[11];
  const float* aout_b   = (const float*)d_in[12];
  const float* w_ih     = (const float*)d_in[13];
  const float* w_hh     = (const float*)d_in[14];
  const float* b_ih     = (const float*)d_in[15];
  const float* b_hh     = (const float*)d_in[16];
  const float* exc_w1   = (const float*)d_in[17];
  const float* exc_b1   = (const float*)d_in[18];
  const float* exc_w2   = (const float*)d_in[19];
  const float* exc_b2   = (const float*)d_in[20];
  const float* opt_w1   = (const float*)d_in[21];
  const float* opt_b1   = (const float*)d_in[22];
  const float* opt_w2   = (const float*)d_in[23];
  const float* opt_b2   = (const float*)d_in[24];
  const float* dec_w1   = (const float*)d_in[25];
  const float* dec_b1   = (const float*)d_in[26];
  const float* dec_w2   = (const float*)d_in[27];
  const float* dec_b2   = (const float*)d_in[28];
  const float* dec_ln_g = (const float*)d_in[29];
  const float* dec_ln_b = (const float*)d_in[30];
  float* out = (float*)d_out;

  char* ws = (char*)d_ws;
  const size_t MB = 1ull << 20;
  u16* xbf  = (u16*)(ws);            // 2MB
  u16* h1   = (u16*)(ws + 2 * MB);   // 16MB
  u16* henc = (u16*)(ws + 18 * MB);  // 16MB
  u16* hbf  = (u16*)(ws + 34 * MB);  // 16MB
  u16* Qb   = (u16*)(ws + 2 * MB);   // reuse h1
  u16* Kb   = (u16*)(ws + 18 * MB);  // reuse henc
  u16* Vt   = (u16*)(ws + 50 * MB);  // 16MB
  u16* sp   = (u16*)(ws + 66 * MB);  // 32MB scores/P
  u16* abuf = (u16*)(ws + 2 * MB);   // reuse Qb
  u16* a_bf = (u16*)(ws + 18 * MB);  // reuse Kb
  u16* pre  = (u16*)(ws + 34 * MB);  // 64MB
  u16* Wf   = (u16*)(ws + 98 * MB);  // 128MB
  u16* mbuf = (u16*)(ws + 2 * MB);   // reuse abuf
  u16* t1   = (u16*)(ws + 18 * MB);  // reuse a_bf
  u16* excp = (u16*)(ws + 34 * MB);  // reuse pre (dead after recurrence)
  u16* t2   = (u16*)(ws + 50 * MB);
  u16* optp = (u16*)(ws + 66 * MB);
  u16* eo   = (u16*)(ws + 82 * MB);
  u16* t3   = (u16*)(ws + 18 * MB);  // reuse t1
  u16* decp = (u16*)(ws + 34 * MB);  // 8MB
  u16*   hbuf   = (u16*)(ws + 226 * MB);                    // 128KB: [2][32768]
  u32*   flags  = (u32*)(ws + 226 * MB + 128 * 1024);       // 16KB
  float* pooled = (float*)(ws + 226 * MB + 160 * 1024);     // 16KB
  float* wgate  = (float*)(ws + 226 * MB + 192 * 1024);     // 64B
  float* cbias  = (float*)(ws + 226 * MB + 224 * 1024);     // 128KB
  u16*   wslot  = (u16*)(ws + 227 * MB);                    // 128MB JIT bf16 weights
  const bool jit = ws_size >= 356ull * MB;

  // h0 = 0 (both hbuf halves) + flags = 0
  hipMemsetAsync(hbuf, 0, 128 * 1024 + 16 * 1024, stream);

  convert_x<<<dim3(512), dim3(256), 0, stream>>>(x, xbf);
  wf_convert<<<dim3(16384), dim3(256), 0, stream>>>(w_hh, Wf);
  comb_bias<<<dim3(32), dim3(256), 0, stream>>>(b_ih, b_hh, cbias);
  gate_pool<<<dim3(16), dim3(256), 0, stream>>>(x, pooled);
  gate_top2<<<dim3(1), dim3(256), 0, stream>>>(pooled, gw, gb, wgate);

  #define CONV(W, N8) convf2b<<<dim3(4096), dim3(256), 0, stream>>>(W, wslot, N8)

  // enc: relu(x@W1^T+b1) @ W2^T + b2 -> LN
  if (jit){
    CONV(enc_w1, 1048576);
    gemm_bt<1, 0, true, true, false><<<dim3(512), dim3(256), 0, stream>>>(
        xbf, wslot, h1, nullptr, nullptr, enc_b1, 2048, 1024, 1024, 1024,
        0LL, 2048LL * 1024, 1024LL * 2048, 2048, 8, 16, 1.f);
    CONV(enc_w2, 2097152);
    gemm_bt<1, 0, true, false, false><<<dim3(512), dim3(256), 0, stream>>>(
        h1, wslot, henc, nullptr, nullptr, enc_b2, 2048, 2048, 2048, 2048,
        1024LL * 2048, 2048LL * 2048, 1024LL * 2048, 2048, 8, 16, 1.f);
  } else {
    gemm_bt<0, 0, true, true, false><<<dim3(512), dim3(256), 0, stream>>>(
        xbf, enc_w1, h1, nullptr, nullptr, enc_b1, 2048, 1024, 1024, 1024,
        0LL, 2048LL * 1024, 1024LL * 2048, 2048, 8, 16, 1.f);
    gemm_bt<0, 0, true, false, false><<<dim3(512), dim3(256), 0, stream>>>(
        h1, enc_w2, henc, nullptr, nullptr, enc_b2, 2048, 2048, 2048, 2048,
        1024LL * 2048, 2048LL * 2048, 1024LL * 2048, 2048, 8, 16, 1.f);
  }
  ln2048<<<dim3(4096), dim3(256), 0, stream>>>(henc, hbf, enc_ln_g, enc_ln_b);

  // attention
  if (jit){
    CONV(ain_w, 6291456);
    gemm_bt<1, 1, true, false, false><<<dim3(1536), dim3(256), 0, stream>>>(
        hbf, wslot, Qb, Kb, Vt, ain_b, 6144, 2048, 2048, 2048,
        1024LL * 2048, 6144LL * 2048, 0LL, 6144, 8, 48, 1.f);
  } else {
    gemm_bt<0, 1, true, false, false><<<dim3(1536), dim3(256), 0, stream>>>(
        hbf, ain_w, Qb, Kb, Vt, ain_b, 6144, 2048, 2048, 2048,
        1024LL * 2048, 6144LL * 2048, 0LL, 6144, 8, 48, 1.f);
  }
  gemm_bt<1, 0, false, false, true><<<dim3(1024), dim3(256), 0, stream>>>(
      Qb, Kb, sp, nullptr, nullptr, nullptr, 256, 128, 128, 128,
      32768LL, 32768LL, 65536LL, 0, 2, 2, 0.08838834764831845f);
  softmax256<<<dim3(16384), dim3(256), 0, stream>>>(sp);
  gemm_bt<1, 2, false, false, false><<<dim3(512), dim3(256), 0, stream>>>(
      sp, Vt, abuf, nullptr, nullptr, nullptr, 128, 256, 256, 256,
      65536LL, 32768LL, 0LL, 0, 2, 1, 1.f);
  if (jit){
    CONV(aout_w, 2097152);
    gemm_bt<1, 0, true, false, false><<<dim3(512), dim3(256), 0, stream>>>(
        abuf, wslot, a_bf, nullptr, nullptr, aout_b, 2048, 2048, 2048, 2048,
        1024LL * 2048, 2048LL * 2048, 1024LL * 2048, 2048, 8, 16, 1.f);
    // LSTM: pre = a @ W_ih^T + b_ih + b_hh
    CONV(w_ih, 8388608);
    gemm_bt<1, 0, true, false, false><<<dim3(2048), dim3(256), 0, stream>>>(
        a_bf, wslot, pre, nullptr, nullptr, cbias, 8192, 2048, 2048, 2048,
        1024LL * 2048, 8192LL * 2048, 1024LL * 8192, 8192, 8, 64, 1.f);
  } else {
    gemm_bt<0, 0, true, false, false><<<dim3(512), dim3(256), 0, stream>>>(
        abuf, aout_w, a_bf, nullptr, nullptr, aout_b, 2048, 2048, 2048, 2048,
        1024LL * 2048, 2048LL * 2048, 1024LL * 2048, 2048, 8, 16, 1.f);
    gemm_bt<0, 0, true, false, false><<<dim3(2048), dim3(256), 0, stream>>>(
        a_bf, w_ih, pre, nullptr, nullptr, cbias, 8192, 2048, 2048, 2048,
        1024LL * 2048, 8192LL * 2048, 1024LL * 8192, 8192, 8, 64, 1.f);
  }
  lstm_persist<<<dim3(256), dim3(512), 0, stream>>>(Wf, pre, hbuf, mbuf, flags);

  // exc / opt / dec
  if (jit){
    CONV(exc_w1, 2097152);
    gemm_bt<1, 0, true, true, false><<<dim3(512), dim3(256), 0, stream>>>(
        mbuf, wslot, t1, nullptr, nullptr, exc_b1, 2048, 2048, 2048, 2048,
        1024LL * 2048, 2048LL * 2048, 1024LL * 2048, 2048, 8, 16, 1.f);
    CONV(exc_w2, 2097152);
    gemm_bt<1, 0, true, false, false><<<dim3(512), dim3(256), 0, stream>>>(
        t1, wslot, excp, nullptr, nullptr, exc_b2, 2048, 2048, 2048, 2048,
        1024LL * 2048, 2048LL * 2048, 1024LL * 2048, 2048, 8, 16, 1.f);
    CONV(opt_w1, 2097152);
    gemm_bt<1, 0, true, true, false><<<dim3(512), dim3(256), 0, stream>>>(
        mbuf, wslot, t2, nullptr, nullptr, opt_b1, 2048, 2048, 2048, 2048,
        1024LL * 2048, 2048LL * 2048, 1024LL * 2048, 2048, 8, 16, 1.f);
    CONV(opt_w2, 2097152);
    gemm_bt<1, 0, true, false, false><<<dim3(512), dim3(256), 0, stream>>>(
        t2, wslot, optp, nullptr, nullptr, opt_b2, 2048, 2048, 2048, 2048,
        1024LL * 2048, 2048LL * 2048, 1024LL * 2048, 2048, 8, 16, 1.f);
  } else {
    gemm_bt<0, 0, true, true, false><<<dim3(512), dim3(256), 0, stream>>>(
        mbuf, exc_w1, t1, nullptr, nullptr, exc_b1, 2048, 2048, 2048, 2048,
        1024LL * 2048, 2048LL * 2048, 1024LL * 2048, 2048, 8, 16, 1.f);
    gemm_bt<0, 0, true, false, false><<<dim3(512), dim3(256), 0, stream>>>(
        t1, exc_w2, excp, nullptr, nullptr, exc_b2, 2048, 2048, 2048, 2048,
        1024LL * 2048, 2048LL * 2048, 1024LL * 2048, 2048, 8, 16, 1.f);
    gemm_bt<0, 0, true, true, false><<<dim3(512), dim3(256), 0, stream>>>(
        mbuf, opt_w1, t2, nullptr, nullptr, opt_b1, 2048, 2048, 2048, 2048,
        1024LL * 2048, 2048LL * 2048, 1024LL * 2048, 2048, 8, 16, 1.f);
    gemm_bt<0, 0, true, false, false><<<dim3(512), dim3(256), 0, stream>>>(
        t2, opt_w2, optp, nullptr, nullptr, opt_b2, 2048, 2048, 2048, 2048,
        1024LL * 2048, 2048LL * 2048, 1024LL * 2048, 2048, 8, 16, 1.f);
  }
  eo_kernel<<<dim3(4096), dim3(256), 0, stream>>>(excp, optp, eo);
  if (jit){
    CONV(dec_w1, 2097152);
    gemm_bt<1, 0, true, true, false><<<dim3(512), dim3(256), 0, stream>>>(
        eo, wslot, t3, nullptr, nullptr, dec_b1, 2048, 2048, 2048, 2048,
        1024LL * 2048, 2048LL * 2048, 1024LL * 2048, 2048, 8, 16, 1.f);
    CONV(dec_w2, 1048576);
    gemm_bt<1, 0, true, false, false><<<dim3(256), dim3(256), 0, stream>>>(
        t3, wslot, decp, nullptr, nullptr, dec_b2, 1024, 2048, 2048, 2048,
        1024LL * 2048, 1024LL * 2048, 1024LL * 1024, 1024, 8, 8, 1.f);
  } else {
    gemm_bt<0, 0, true, true, false><<<dim3(512), dim3(256), 0, stream>>>(
        eo, dec_w1, t3, nullptr, nullptr, dec_b1, 2048, 2048, 2048, 2048,
        1024LL * 2048, 2048LL * 2048, 1024LL * 2048, 2048, 8, 16, 1.f);
    gemm_bt<0, 0, true, false, false><<<dim3(256), dim3(256), 0, stream>>>(
        t3, dec_w2, decp, nullptr, nullptr, dec_b2, 1024, 2048, 2048, 2048,
        1024LL * 2048, 1024LL * 2048, 1024LL * 1024, 1024, 8, 8, 1.f);
  }
  #undef CONV

  final_combine<<<dim3(1024), dim3(256), 0, stream>>>(decp, wgate, dec_ln_g, dec_ln_b, out);
}